// Round 5
// baseline (97.188 us; speedup 1.0000x reference)
//
#include <hip/hip_runtime.h>

// Chamfer distance L2 via MFMA: B=8, N=M=8192, fp32 3D points.
// d(q,t) = ||q||^2 + ||t||^2 - 2 q.t  computed as ONE mfma_f32_16x16x32_bf16
// per 16x16 tile: per-point 16-slot bf16 k-vectors with hi/lo splits:
//   A(q): [-2xh,-2xl,-2xh,-2xl, -2yh,-2yl,-2yh,-2yl, -2zh,-2zl,-2zh,-2zl, wh,wl,1,1]
//   B(t): [ xh,  xh,  xl,  xl,   yh,  yh,  yl,  yl,   zh,  zh,  zl,  zl, 1,1,wh,wl]
// slot products sum to -2(xh+xl)(x'h+x'l)... + ||q||^2 + ||t||^2 = d exactly
// up to ~2^-18 split error (mean output error ~1e-5 << 9.3e-4 threshold).
// A/B fragment k-slot placement is layout-agnostic (same (block,elem)->k map
// on both operands => products pair correctly under any HW permutation).
// One matrix serves BOTH directions: row-min -> dist1, col-min -> dist2.
// C/D layout (m89-verified): col = lane&15, row = (lane>>4)*4 + reg.

typedef float  f32x4  __attribute__((ext_vector_type(4)));
typedef __bf16 bf16x4 __attribute__((ext_vector_type(4)));
typedef __bf16 bf16x8 __attribute__((ext_vector_type(8)));

constexpr int B  = 8;
constexpr int N  = 8192;
constexpr int BN = B * N;       // 65536 points per set
constexpr int NQ = 2 * BN;      // 131072 min-entries (both directions)

__device__ inline ushort f2bh(float x) {            // fp32 -> bf16 RNE
  unsigned u = __float_as_uint(x);
  return (ushort)((u + 0x7FFFu + ((u >> 16) & 1u)) >> 16);
}
__device__ inline float bh2f(ushort h) { return __uint_as_float(((unsigned)h) << 16); }
__device__ inline unsigned fkey(float f) {           // order-preserving key
  unsigned u = __float_as_uint(f);
  return (u & 0x80000000u) ? ~u : (u | 0x80000000u);
}
__device__ inline float funkey(unsigned k) {
  return __uint_as_float((k & 0x80000000u) ? (k & 0x7FFFFFFFu) : ~k);
}

__global__ __launch_bounds__(256) void pack_mfma_kernel(
    const float* __restrict__ xyz1, const float* __restrict__ xyz2,
    ushort* __restrict__ kvA, ushort* __restrict__ kvB) {
  int i = blockIdx.x * 256 + threadIdx.x;   // [0, 2*BN)
  bool isA = i < BN;
  const float* src = isA ? xyz1 : xyz2;
  int j = isA ? i : i - BN;
  float x = src[3 * j], y = src[3 * j + 1], z = src[3 * j + 2];
  float w = fmaf(x, x, fmaf(y, y, z * z));
  ushort xh = f2bh(x), yh = f2bh(y), zh = f2bh(z), wh = f2bh(w);
  ushort xl = f2bh(x - bh2f(xh)), yl = f2bh(y - bh2f(yh));
  ushort zl = f2bh(z - bh2f(zh)), wl = f2bh(w - bh2f(wh));
  const unsigned ONE2 = 0x3F803F80u;                 // (1.0, 1.0) bf16
  unsigned pw = (unsigned)wh | ((unsigned)wl << 16);
  if (isA) {
    ushort axh = f2bh(-2.f * bh2f(xh)), axl = f2bh(-2.f * bh2f(xl));
    ushort ayh = f2bh(-2.f * bh2f(yh)), ayl = f2bh(-2.f * bh2f(yl));
    ushort azh = f2bh(-2.f * bh2f(zh)), azl = f2bh(-2.f * bh2f(zl));
    unsigned px = (unsigned)axh | ((unsigned)axl << 16);
    unsigned py = (unsigned)ayh | ((unsigned)ayl << 16);
    unsigned pz = (unsigned)azh | ((unsigned)azl << 16);
    *(uint4*)(kvA + (size_t)j * 16)     = make_uint4(px, px, py, py);
    *(uint4*)(kvA + (size_t)j * 16 + 8) = make_uint4(pz, pz, pw, ONE2);
  } else {
    unsigned bx0 = (unsigned)xh | ((unsigned)xh << 16);
    unsigned bx1 = (unsigned)xl | ((unsigned)xl << 16);
    unsigned by0 = (unsigned)yh | ((unsigned)yh << 16);
    unsigned by1 = (unsigned)yl | ((unsigned)yl << 16);
    unsigned bz0 = (unsigned)zh | ((unsigned)zh << 16);
    unsigned bz1 = (unsigned)zl | ((unsigned)zl << 16);
    *(uint4*)(kvB + (size_t)j * 16)     = make_uint4(bx0, bx1, by0, by1);
    *(uint4*)(kvB + (size_t)j * 16 + 8) = make_uint4(bz0, bz1, ONE2, pw);
  }
}

// grid = 8(batch) x 16(query group of 512) x 8(target chunk of 1024) = 1024
// block: 4 waves; wave owns 128 queries (8 i-tiles), sweeps 64 j-tiles.
__global__ __launch_bounds__(256, 4) void nn_mfma_kernel(
    const ushort* __restrict__ kvA, const ushort* __restrict__ kvB,
    unsigned* __restrict__ pmin1, unsigned* __restrict__ pmin2) {
  __shared__ ushort kb[1024 * 16];                   // 32 KB target kvecs
  const int bid = blockIdx.x;
  const int c   = bid & 7;
  const int ig  = (bid >> 3) & 15;
  const int b   = bid >> 7;
  const int tid = threadIdx.x;
  const int w = tid >> 6, lane = tid & 63;
  const int bb = lane >> 4, nn = lane & 15;

  {   // stage 1024 targets' kvecs
    const uint4* src = (const uint4*)(kvB + (size_t)(b * N + c * 1024) * 16);
    uint4* dst = (uint4*)kb;
    #pragma unroll
    for (int i = 0; i < 8; ++i) dst[tid + i * 256] = src[tid + i * 256];
  }
  __syncthreads();

  const bf16x4 z4 = {(__bf16)0.f, (__bf16)0.f, (__bf16)0.f, (__bf16)0.f};
  const f32x4 cz = {0.f, 0.f, 0.f, 0.f};

  const int qwb = b * N + ig * 512 + w * 128;        // wave's first query
  bf16x8 af[8];
  #pragma unroll
  for (int it = 0; it < 8; ++it) {
    bf16x4 lo = *(const bf16x4*)(kvA + (size_t)(qwb + it * 16 + nn) * 16 + bb * 4);
    af[it] = __builtin_shufflevector(lo, z4, 0, 1, 2, 3, 4, 5, 6, 7);
  }

  float rmin[8][4];
  #pragma unroll
  for (int it = 0; it < 8; ++it) {
    rmin[it][0] = 3.4e38f; rmin[it][1] = 3.4e38f;
    rmin[it][2] = 3.4e38f; rmin[it][3] = 3.4e38f;
  }

  for (int jt = 0; jt < 64; ++jt) {
    bf16x4 blo = *(const bf16x4*)(kb + (jt * 16 + nn) * 16 + bb * 4);
    bf16x8 bfr = __builtin_shufflevector(blo, z4, 0, 1, 2, 3, 4, 5, 6, 7);
    float colv = 3.4e38f;
    #pragma unroll
    for (int it = 0; it < 8; ++it) {
      f32x4 acc = __builtin_amdgcn_mfma_f32_16x16x32_bf16(af[it], bfr, cz, 0, 0, 0);
      rmin[it][0] = fminf(rmin[it][0], acc[0]);
      rmin[it][1] = fminf(rmin[it][1], acc[1]);
      rmin[it][2] = fminf(rmin[it][2], acc[2]);
      rmin[it][3] = fminf(rmin[it][3], acc[3]);
      colv = fminf(colv, fminf(fminf(acc[0], acc[1]), fminf(acc[2], acc[3])));
    }
    // col-min: fold the 4 lane-blocks (rows), then 16 lanes hold 16 targets
    colv = fminf(colv, __shfl_xor(colv, 16));
    colv = fminf(colv, __shfl_xor(colv, 32));
    if (lane < 16)
      atomicMin(&pmin2[b * N + c * 1024 + jt * 16 + lane], fkey(colv));
  }

  // row-min epilogue: reduce across the 16 col-class lanes per query
  #pragma unroll
  for (int it = 0; it < 8; ++it) {
    #pragma unroll
    for (int r = 0; r < 4; ++r) {
      float v = rmin[it][r];
      v = fminf(v, __shfl_xor(v, 1));
      v = fminf(v, __shfl_xor(v, 2));
      v = fminf(v, __shfl_xor(v, 4));
      v = fminf(v, __shfl_xor(v, 8));
      if (nn == 0)
        atomicMin(&pmin1[qwb + it * 16 + bb * 4 + r], fkey(v));
    }
  }
}

__global__ __launch_bounds__(256) void reduce_final_kernel(
    const unsigned* __restrict__ pmin, float* __restrict__ blocksums) {
  int gq = blockIdx.x * 256 + threadIdx.x;   // [0, NQ)
  float v = funkey(pmin[gq]);
  #pragma unroll
  for (int off = 32; off > 0; off >>= 1) v += __shfl_down(v, off);
  __shared__ float ssum[4];
  const int lane = threadIdx.x & 63, wid = threadIdx.x >> 6;
  if (lane == 0) ssum[wid] = v;
  __syncthreads();
  if (threadIdx.x == 0)
    blocksums[blockIdx.x] = ssum[0] + ssum[1] + ssum[2] + ssum[3];
}

__global__ __launch_bounds__(512) void finalize_sums_kernel(
    const float* __restrict__ blocksums, float* __restrict__ out) {
  float v = blocksums[threadIdx.x];
  #pragma unroll
  for (int off = 32; off > 0; off >>= 1) v += __shfl_down(v, off);
  __shared__ float ssum[8];
  const int lane = threadIdx.x & 63, wid = threadIdx.x >> 6;
  if (lane == 0) ssum[wid] = v;
  __syncthreads();
  if (threadIdx.x == 0) {
    float s = 0.f;
    #pragma unroll
    for (int w = 0; w < 8; ++w) s += ssum[w];
    out[0] = s * (1.0f / 65536.0f);   // mean1 + mean2 (B*N == B*M)
  }
}

// ---------- round-1 proven fallback (if ws too small) ----------
__global__ __launch_bounds__(256) void pack4_kernel(
    const float* __restrict__ xyz1, const float* __restrict__ xyz2,
    float4* __restrict__ p1, float4* __restrict__ p2) {
  int i = blockIdx.x * 256 + threadIdx.x;
  const float* s = (i < BN) ? xyz1 : xyz2;
  float4* d      = (i < BN) ? p1 : p2;
  int j          = (i < BN) ? i : (i - BN);
  float x = s[3 * j], y = s[3 * j + 1], z = s[3 * j + 2];
  d[j] = make_float4(x, y, z, fmaf(x, x, fmaf(y, y, z * z)));
}

__global__ __launch_bounds__(256) void nn_packed_kernel(
    const float4* __restrict__ p1, const float4* __restrict__ p2,
    float* __restrict__ blocksums) {
  const int bid   = blockIdx.x;
  const int dir   = bid >> 8;
  const int idx   = bid & 255;
  const int b     = idx >> 5;
  const int chunk = idx & 31;
  const float4* __restrict__ q = (dir ? p2 : p1) + b * N + chunk * 256;
  const float4* __restrict__ t = (dir ? p1 : p2) + b * N;

  float4 qv = q[threadIdx.x];
  const float qx = -2.0f * qv.x, qy = -2.0f * qv.y, qz = -2.0f * qv.z;

  float mn0 = 3.4e38f, mn1 = 3.4e38f, mn2 = 3.4e38f, mn3 = 3.4e38f;
  #pragma unroll 2
  for (int m = 0; m < N; m += 4) {
    float4 t0 = t[m + 0], t1 = t[m + 1], t2 = t[m + 2], t3 = t[m + 3];
    float d0 = fmaf(qx, t0.x, fmaf(qy, t0.y, fmaf(qz, t0.z, t0.w)));
    float d1 = fmaf(qx, t1.x, fmaf(qy, t1.y, fmaf(qz, t1.z, t1.w)));
    float d2 = fmaf(qx, t2.x, fmaf(qy, t2.y, fmaf(qz, t2.z, t2.w)));
    float d3 = fmaf(qx, t3.x, fmaf(qy, t3.y, fmaf(qz, t3.z, t3.w)));
    mn0 = fminf(mn0, d0); mn1 = fminf(mn1, d1);
    mn2 = fminf(mn2, d2); mn3 = fminf(mn3, d3);
  }
  float v = qv.w + fminf(fminf(mn0, mn1), fminf(mn2, mn3));

  #pragma unroll
  for (int off = 32; off > 0; off >>= 1) v += __shfl_down(v, off);
  __shared__ float ssum[4];
  const int lane = threadIdx.x & 63, wid = threadIdx.x >> 6;
  if (lane == 0) ssum[wid] = v;
  __syncthreads();
  if (threadIdx.x == 0)
    blocksums[bid] = ssum[0] + ssum[1] + ssum[2] + ssum[3];
}

extern "C" void kernel_launch(void* const* d_in, const int* in_sizes, int n_in,
                              void* d_out, int out_size, void* d_ws, size_t ws_size,
                              hipStream_t stream) {
  const float* xyz1 = (const float*)d_in[0];
  const float* xyz2 = (const float*)d_in[1];
  float* out = (float*)d_out;

  // ws: kvA(2MB) kvB(2MB) pmin(512KB) blocksums(2KB)
  ushort* kvA = (ushort*)d_ws;
  ushort* kvB = kvA + (size_t)BN * 16;
  unsigned* pmin = (unsigned*)(kvB + (size_t)BN * 16);
  float* blocksums = (float*)(pmin + NQ);
  const size_t need = (size_t)BN * 16 * 2 * 2 + (size_t)NQ * 4 + 512 * sizeof(float);

  if (ws_size >= need) {
    pack_mfma_kernel<<<(2 * BN) / 256, 256, 0, stream>>>(xyz1, xyz2, kvA, kvB);
    hipMemsetAsync(pmin, 0xFF, (size_t)NQ * 4, stream);
    nn_mfma_kernel<<<1024, 256, 0, stream>>>(kvA, kvB, pmin, pmin + BN);
    reduce_final_kernel<<<NQ / 256, 256, 0, stream>>>(pmin, blocksums);
    finalize_sums_kernel<<<1, 512, 0, stream>>>(blocksums, out);
  } else {
    float4* p1 = (float4*)d_ws;
    float4* p2 = p1 + BN;
    float* bsum = (float*)(p2 + BN);
    pack4_kernel<<<(2 * BN) / 256, 256, 0, stream>>>(xyz1, xyz2, p1, p2);
    nn_packed_kernel<<<512, 256, 0, stream>>>(p1, p2, bsum);
    finalize_sums_kernel<<<1, 512, 0, stream>>>(bsum, out);
  }
}

// Round 7
// 75.473 us; speedup vs baseline: 1.2877x; 1.2877x over previous
//
#include <hip/hip_runtime.h>

// Chamfer distance L2 via MFMA (R7 = R6 minus all inline asm).
// d(q,t) = ||q||^2 + ||t||^2 - 2 q.t as mfma_f32_32x32x16_bf16 (K=16 exactly
// matches the 16-slot hi/lo-split bf16 kvec, 1024 pairs/MFMA).
// Two orientations (dir0: set1 rows vs set2 cols; dir1: swapped) so each
// direction's NN-min is a pure per-lane register fminf accumulation.
// R6 failed (absmax 0.29 ~= min over last tile only): suspected inline-asm
// v_min3 on MFMA results (rule-#18 class hazard). R7 uses plain fminf
// (R5-proven exact against intrinsic results) and __syncthreads-guarded
// LDS transpose epilogue. No asm, no atomics, fully deterministic.
// kvec slot pairing is bijection-robust (A and B share the (laneHalf,elem)->k
// map); C/D: col=lane&31, row=(r&3)+8*(r>>2)+4*(lane>>5) [m74/m101].

typedef float  f32x16 __attribute__((ext_vector_type(16)));
typedef __bf16 bf16x8 __attribute__((ext_vector_type(8)));

constexpr int B  = 8;
constexpr int N  = 8192;
constexpr int BN = B * N;       // 65536 points per set
constexpr int NQ = 2 * BN;      // 131072 rows total (both directions)
constexpr int CO = 4;           // outer target chunks (part slabs)

__device__ inline ushort f2bh(float x) {            // fp32 -> bf16 RNE
  unsigned u = __float_as_uint(x);
  return (ushort)((u + 0x7FFFu + ((u >> 16) & 1u)) >> 16);
}
__device__ inline float bh2f(ushort h) { return __uint_as_float(((unsigned)h) << 16); }

// A-form: [-2xh,-2xl,-2xh,-2xl, -2yh,..., -2zh,..., wh,wl,1,1]
// B-form: [ xh,  xh,  xl,  xl,   yh, ...,  zh, ..., 1,1,wh,wl]
__global__ __launch_bounds__(256) void pack_both_kernel(
    const float* __restrict__ xyz1, const float* __restrict__ xyz2,
    ushort* __restrict__ kvA1, ushort* __restrict__ kvB1,
    ushort* __restrict__ kvA2, ushort* __restrict__ kvB2) {
  int i = blockIdx.x * 256 + threadIdx.x;   // [0, 2*BN)
  bool s1 = i < BN;
  const float* src = s1 ? xyz1 : xyz2;
  ushort* kvA = s1 ? kvA1 : kvA2;
  ushort* kvB = s1 ? kvB1 : kvB2;
  int j = s1 ? i : i - BN;
  float x = src[3 * j], y = src[3 * j + 1], z = src[3 * j + 2];
  float w = fmaf(x, x, fmaf(y, y, z * z));
  ushort xh = f2bh(x), yh = f2bh(y), zh = f2bh(z), wh = f2bh(w);
  ushort xl = f2bh(x - bh2f(xh)), yl = f2bh(y - bh2f(yh));
  ushort zl = f2bh(z - bh2f(zh)), wl = f2bh(w - bh2f(wh));
  const unsigned ONE2 = 0x3F803F80u;                 // (1.0, 1.0) bf16
  unsigned pw = (unsigned)wh | ((unsigned)wl << 16);
  {
    ushort axh = f2bh(-2.f * bh2f(xh)), axl = f2bh(-2.f * bh2f(xl));
    ushort ayh = f2bh(-2.f * bh2f(yh)), ayl = f2bh(-2.f * bh2f(yl));
    ushort azh = f2bh(-2.f * bh2f(zh)), azl = f2bh(-2.f * bh2f(zl));
    unsigned px = (unsigned)axh | ((unsigned)axl << 16);
    unsigned py = (unsigned)ayh | ((unsigned)ayl << 16);
    unsigned pz = (unsigned)azh | ((unsigned)azl << 16);
    *(uint4*)(kvA + (size_t)j * 16)     = make_uint4(px, px, py, py);
    *(uint4*)(kvA + (size_t)j * 16 + 8) = make_uint4(pz, pz, pw, ONE2);
  }
  {
    unsigned bx0 = (unsigned)xh | ((unsigned)xh << 16);
    unsigned bx1 = (unsigned)xl | ((unsigned)xl << 16);
    unsigned by0 = (unsigned)yh | ((unsigned)yh << 16);
    unsigned by1 = (unsigned)yl | ((unsigned)yl << 16);
    unsigned bz0 = (unsigned)zh | ((unsigned)zh << 16);
    unsigned bz1 = (unsigned)zl | ((unsigned)zl << 16);
    *(uint4*)(kvB + (size_t)j * 16)     = make_uint4(bx0, bx1, by0, by1);
    *(uint4*)(kvB + (size_t)j * 16 + 8) = make_uint4(bz0, bz1, ONE2, pw);
  }
}

// grid = dir(2) x b(8) x c(4) x qg(16) = 1024 blocks, qg fastest (16
// consecutive blocks stream the same 2048-target chunk -> L2-hot).
// Block: 4 waves; wave owns 128 A-rows (4 tiles of 32); sweeps 2048 targets
// staged in LDS as 2 x 1024-point halves (32 KB).
__global__ __launch_bounds__(256, 3) void nn_mfma32_kernel(
    const ushort* __restrict__ kvA1, const ushort* __restrict__ kvB1,
    const ushort* __restrict__ kvA2, const ushort* __restrict__ kvB2,
    float* __restrict__ part) {
  __shared__ __align__(16) ushort kb[1024 * 16];     // 32 KB target kvecs
  __shared__ float red[4][32][36];                   // padded transpose buf
  const int bid = blockIdx.x;
  const int qg  = bid & 15;
  const int c   = (bid >> 4) & 3;
  const int b   = (bid >> 6) & 7;
  const int dir = (bid >> 9) & 1;
  const ushort* __restrict__ kvA = dir ? kvA2 : kvA1;
  const ushort* __restrict__ kvB = dir ? kvB1 : kvB2;

  const int tid = threadIdx.x;
  const int w = tid >> 6, lane = tid & 63;
  const int cl = lane & 31, hi = lane >> 5;

  // A fragments: 4 tiles x 32 rows; lane holds row cl, k-half hi
  const int qbase = b * N + qg * 512 + w * 128;
  bf16x8 af[4];
  #pragma unroll
  for (int a = 0; a < 4; ++a)
    af[a] = *(const bf16x8*)(kvA + (size_t)(qbase + a * 32 + cl) * 16 + hi * 8);

  float rmin[4][16];
  #pragma unroll
  for (int a = 0; a < 4; ++a)
    #pragma unroll
    for (int r = 0; r < 16; ++r) rmin[a][r] = 3.4e38f;

  const f32x16 cz = {0.f, 0.f, 0.f, 0.f, 0.f, 0.f, 0.f, 0.f,
                     0.f, 0.f, 0.f, 0.f, 0.f, 0.f, 0.f, 0.f};
  const int tbase = b * N + c * 2048;

  #pragma unroll 1
  for (int half = 0; half < 2; ++half) {
    if (half) __syncthreads();                       // all waves done with kb
    {   // stage 1024 targets (32 KB)
      const uint4* src = (const uint4*)(kvB + (size_t)(tbase + half * 1024) * 16);
      uint4* dst = (uint4*)kb;
      #pragma unroll
      for (int i = 0; i < 8; ++i) dst[tid + i * 256] = src[tid + i * 256];
    }
    __syncthreads();

    #pragma unroll 1
    for (int jp = 0; jp < 16; ++jp) {               // 2 target tiles per iter
      const ushort* kp = kb + (jp * 64 + cl) * 16 + hi * 8;
      bf16x8 bf0 = *(const bf16x8*)(kp);
      bf16x8 bf1 = *(const bf16x8*)(kp + 32 * 16);
      #pragma unroll
      for (int a = 0; a < 4; ++a) {
        f32x16 acc0 = __builtin_amdgcn_mfma_f32_32x32x16_bf16(af[a], bf0, cz, 0, 0, 0);
        f32x16 acc1 = __builtin_amdgcn_mfma_f32_32x32x16_bf16(af[a], bf1, cz, 0, 0, 0);
        #pragma unroll
        for (int r = 0; r < 16; ++r)
          rmin[a][r] = fminf(rmin[a][r], fminf(acc0[r], acc1[r]));
      }
    }
  }

  // epilogue: per a-tile, transpose via padded LDS, per-row fold, plain store
  #pragma unroll 1
  for (int a = 0; a < 4; ++a) {
    __syncthreads();                                 // guard red reuse
    #pragma unroll
    for (int r = 0; r < 16; ++r) {
      int row = (r & 3) + 8 * (r >> 2) + 4 * hi;     // m74/m101 C/D layout
      red[w][row][cl] = rmin[a][r];
    }
    __syncthreads();
    if (lane < 32) {
      float m = 3.4e38f;
      #pragma unroll
      for (int i = 0; i < 8; ++i) {
        float4 v = *(const float4*)&red[w][lane][i * 4];
        m = fminf(m, fminf(fminf(v.x, v.y), fminf(v.z, v.w)));
      }
      part[(size_t)c * NQ + dir * BN + qbase + a * 32 + lane] = m;
    }
  }
}

__global__ __launch_bounds__(256) void reduce_final_kernel(
    const float* __restrict__ part, float* __restrict__ blocksums) {
  int gq = blockIdx.x * 256 + threadIdx.x;   // [0, NQ)
  float v = part[gq];
  #pragma unroll
  for (int cc = 1; cc < CO; ++cc) v = fminf(v, part[(size_t)cc * NQ + gq]);
  #pragma unroll
  for (int off = 32; off > 0; off >>= 1) v += __shfl_down(v, off);
  __shared__ float ssum[4];
  const int lane = threadIdx.x & 63, wid = threadIdx.x >> 6;
  if (lane == 0) ssum[wid] = v;
  __syncthreads();
  if (threadIdx.x == 0)
    blocksums[blockIdx.x] = ssum[0] + ssum[1] + ssum[2] + ssum[3];
}

__global__ __launch_bounds__(512) void finalize_sums_kernel(
    const float* __restrict__ blocksums, float* __restrict__ out) {
  float v = blocksums[threadIdx.x];
  #pragma unroll
  for (int off = 32; off > 0; off >>= 1) v += __shfl_down(v, off);
  __shared__ float ssum[8];
  const int lane = threadIdx.x & 63, wid = threadIdx.x >> 6;
  if (lane == 0) ssum[wid] = v;
  __syncthreads();
  if (threadIdx.x == 0) {
    float s = 0.f;
    #pragma unroll
    for (int w = 0; w < 8; ++w) s += ssum[w];
    out[0] = s * (1.0f / 65536.0f);   // mean1 + mean2 (B*N == B*M)
  }
}

// ---------- round-1 proven fallback (if ws too small) ----------
__global__ __launch_bounds__(256) void pack4_kernel(
    const float* __restrict__ xyz1, const float* __restrict__ xyz2,
    float4* __restrict__ p1, float4* __restrict__ p2) {
  int i = blockIdx.x * 256 + threadIdx.x;
  const float* s = (i < BN) ? xyz1 : xyz2;
  float4* d      = (i < BN) ? p1 : p2;
  int j          = (i < BN) ? i : (i - BN);
  float x = s[3 * j], y = s[3 * j + 1], z = s[3 * j + 2];
  d[j] = make_float4(x, y, z, fmaf(x, x, fmaf(y, y, z * z)));
}

__global__ __launch_bounds__(256) void nn_packed_kernel(
    const float4* __restrict__ p1, const float4* __restrict__ p2,
    float* __restrict__ blocksums) {
  const int bid   = blockIdx.x;
  const int dir   = bid >> 8;
  const int idx   = bid & 255;
  const int b     = idx >> 5;
  const int chunk = idx & 31;
  const float4* __restrict__ q = (dir ? p2 : p1) + b * N + chunk * 256;
  const float4* __restrict__ t = (dir ? p1 : p2) + b * N;

  float4 qv = q[threadIdx.x];
  const float qx = -2.0f * qv.x, qy = -2.0f * qv.y, qz = -2.0f * qv.z;

  float mn0 = 3.4e38f, mn1 = 3.4e38f, mn2 = 3.4e38f, mn3 = 3.4e38f;
  #pragma unroll 2
  for (int m = 0; m < N; m += 4) {
    float4 t0 = t[m + 0], t1 = t[m + 1], t2 = t[m + 2], t3 = t[m + 3];
    float d0 = fmaf(qx, t0.x, fmaf(qy, t0.y, fmaf(qz, t0.z, t0.w)));
    float d1 = fmaf(qx, t1.x, fmaf(qy, t1.y, fmaf(qz, t1.z, t1.w)));
    float d2 = fmaf(qx, t2.x, fmaf(qy, t2.y, fmaf(qz, t2.z, t2.w)));
    float d3 = fmaf(qx, t3.x, fmaf(qy, t3.y, fmaf(qz, t3.z, t3.w)));
    mn0 = fminf(mn0, d0); mn1 = fminf(mn1, d1);
    mn2 = fminf(mn2, d2); mn3 = fminf(mn3, d3);
  }
  float v = qv.w + fminf(fminf(mn0, mn1), fminf(mn2, mn3));

  #pragma unroll
  for (int off = 32; off > 0; off >>= 1) v += __shfl_down(v, off);
  __shared__ float ssum[4];
  const int lane = threadIdx.x & 63, wid = threadIdx.x >> 6;
  if (lane == 0) ssum[wid] = v;
  __syncthreads();
  if (threadIdx.x == 0)
    blocksums[bid] = ssum[0] + ssum[1] + ssum[2] + ssum[3];
}

extern "C" void kernel_launch(void* const* d_in, const int* in_sizes, int n_in,
                              void* d_out, int out_size, void* d_ws, size_t ws_size,
                              hipStream_t stream) {
  const float* xyz1 = (const float*)d_in[0];
  const float* xyz2 = (const float*)d_in[1];
  float* out = (float*)d_out;

  // ws: kvA1,kvB1,kvA2,kvB2 (2MB each) | part (CO*NQ f32 = 2MB) | blocksums
  ushort* kvA1 = (ushort*)d_ws;
  ushort* kvB1 = kvA1 + (size_t)BN * 16;
  ushort* kvA2 = kvB1 + (size_t)BN * 16;
  ushort* kvB2 = kvA2 + (size_t)BN * 16;
  float* part = (float*)(kvB2 + (size_t)BN * 16);
  float* blocksums = part + (size_t)CO * NQ;
  const size_t need = (size_t)BN * 16 * 2 * 4 + (size_t)CO * NQ * 4 +
                      512 * sizeof(float);

  if (ws_size >= need) {
    pack_both_kernel<<<(2 * BN) / 256, 256, 0, stream>>>(
        xyz1, xyz2, kvA1, kvB1, kvA2, kvB2);
    nn_mfma32_kernel<<<1024, 256, 0, stream>>>(kvA1, kvB1, kvA2, kvB2, part);
    reduce_final_kernel<<<NQ / 256, 256, 0, stream>>>(part, blocksums);
    finalize_sums_kernel<<<1, 512, 0, stream>>>(blocksums, out);
  } else {
    float4* p1 = (float4*)d_ws;
    float4* p2 = p1 + BN;
    float* bsum = (float*)(p2 + BN);
    pack4_kernel<<<(2 * BN) / 256, 256, 0, stream>>>(xyz1, xyz2, p1, p2);
    nn_packed_kernel<<<512, 256, 0, stream>>>(p1, p2, bsum);
    finalize_sums_kernel<<<1, 512, 0, stream>>>(bsum, out);
  }
}

// Round 8
// 70.401 us; speedup vs baseline: 1.3805x; 1.0720x over previous
//
#include <hip/hip_runtime.h>

// Chamfer distance L2 via MFMA (R8 = R7 minus register spills).
// R7 passed (absmax 0) but VGPR_Count=72 < ~120 live values and
// WRITE_SIZE=193MB/dispatch (vs 2MB useful) => rmin[4][16] spilled to
// scratch; kernel was scratch-BW bound. R8: 2 A-tiles/wave (rmin 32 regs,
// peak live ~90), grid doubled (qg 32 -> 2048 blocks) for the lost
// parallelism, red transpose buffer aliased onto kb (32KB LDS total).
// Math identical to R7: mfma_f32_32x32x16_bf16 on 16-slot hi/lo-split
// bf16 kvecs; two orientations; per-lane fminf row-min accumulation;
// padded-LDS transpose epilogue; plain deterministic part stores.
// C/D layout: col=lane&31, row=(r&3)+8*(r>>2)+4*(lane>>5) [m74/m101].

typedef float  f32x16 __attribute__((ext_vector_type(16)));
typedef __bf16 bf16x8 __attribute__((ext_vector_type(8)));

constexpr int B  = 8;
constexpr int N  = 8192;
constexpr int BN = B * N;       // 65536 points per set
constexpr int NQ = 2 * BN;      // 131072 rows total (both directions)
constexpr int CO = 4;           // outer target chunks (part slabs)

__device__ inline ushort f2bh(float x) {            // fp32 -> bf16 RNE
  unsigned u = __float_as_uint(x);
  return (ushort)((u + 0x7FFFu + ((u >> 16) & 1u)) >> 16);
}
__device__ inline float bh2f(ushort h) { return __uint_as_float(((unsigned)h) << 16); }

// A-form: [-2xh,-2xl,-2xh,-2xl, -2yh,..., -2zh,..., wh,wl,1,1]
// B-form: [ xh,  xh,  xl,  xl,   yh, ...,  zh, ..., 1,1,wh,wl]
__global__ __launch_bounds__(256) void pack_both_kernel(
    const float* __restrict__ xyz1, const float* __restrict__ xyz2,
    ushort* __restrict__ kvA1, ushort* __restrict__ kvB1,
    ushort* __restrict__ kvA2, ushort* __restrict__ kvB2) {
  int i = blockIdx.x * 256 + threadIdx.x;   // [0, 2*BN)
  bool s1 = i < BN;
  const float* src = s1 ? xyz1 : xyz2;
  ushort* kvA = s1 ? kvA1 : kvA2;
  ushort* kvB = s1 ? kvB1 : kvB2;
  int j = s1 ? i : i - BN;
  float x = src[3 * j], y = src[3 * j + 1], z = src[3 * j + 2];
  float w = fmaf(x, x, fmaf(y, y, z * z));
  ushort xh = f2bh(x), yh = f2bh(y), zh = f2bh(z), wh = f2bh(w);
  ushort xl = f2bh(x - bh2f(xh)), yl = f2bh(y - bh2f(yh));
  ushort zl = f2bh(z - bh2f(zh)), wl = f2bh(w - bh2f(wh));
  const unsigned ONE2 = 0x3F803F80u;                 // (1.0, 1.0) bf16
  unsigned pw = (unsigned)wh | ((unsigned)wl << 16);
  {
    ushort axh = f2bh(-2.f * bh2f(xh)), axl = f2bh(-2.f * bh2f(xl));
    ushort ayh = f2bh(-2.f * bh2f(yh)), ayl = f2bh(-2.f * bh2f(yl));
    ushort azh = f2bh(-2.f * bh2f(zh)), azl = f2bh(-2.f * bh2f(zl));
    unsigned px = (unsigned)axh | ((unsigned)axl << 16);
    unsigned py = (unsigned)ayh | ((unsigned)ayl << 16);
    unsigned pz = (unsigned)azh | ((unsigned)azl << 16);
    *(uint4*)(kvA + (size_t)j * 16)     = make_uint4(px, px, py, py);
    *(uint4*)(kvA + (size_t)j * 16 + 8) = make_uint4(pz, pz, pw, ONE2);
  }
  {
    unsigned bx0 = (unsigned)xh | ((unsigned)xh << 16);
    unsigned bx1 = (unsigned)xl | ((unsigned)xl << 16);
    unsigned by0 = (unsigned)yh | ((unsigned)yh << 16);
    unsigned by1 = (unsigned)yl | ((unsigned)yl << 16);
    unsigned bz0 = (unsigned)zh | ((unsigned)zh << 16);
    unsigned bz1 = (unsigned)zl | ((unsigned)zl << 16);
    *(uint4*)(kvB + (size_t)j * 16)     = make_uint4(bx0, bx1, by0, by1);
    *(uint4*)(kvB + (size_t)j * 16 + 8) = make_uint4(bz0, bz1, ONE2, pw);
  }
}

// grid = dir(2) x b(8) x c(4) x qg(32) = 2048 blocks, qg fastest (32
// consecutive blocks stream the same 2048-target chunk -> L2-hot).
// Block: 4 waves; wave owns 64 A-rows (2 tiles of 32); sweeps 2048 targets
// staged in LDS as 2 x 1024-point halves. red aliases kb (used after all
// kb reads complete + barrier).
__global__ __launch_bounds__(256, 4) void nn_mfma32_kernel(
    const ushort* __restrict__ kvA1, const ushort* __restrict__ kvB1,
    const ushort* __restrict__ kvA2, const ushort* __restrict__ kvB2,
    float* __restrict__ part) {
  __shared__ __align__(16) unsigned char smem[1024 * 32];  // 32 KB
  ushort* kb = (ushort*)smem;                        // [1024][16] kvecs
  float (*red)[32][36] = (float (*)[32][36])smem;    // [4][32][36] = 18 KB

  const int bid = blockIdx.x;
  const int qg  = bid & 31;
  const int c   = (bid >> 5) & 3;
  const int b   = (bid >> 7) & 7;
  const int dir = (bid >> 10) & 1;
  const ushort* __restrict__ kvA = dir ? kvA2 : kvA1;
  const ushort* __restrict__ kvB = dir ? kvB1 : kvB2;

  const int tid = threadIdx.x;
  const int w = tid >> 6, lane = tid & 63;
  const int cl = lane & 31, hi = lane >> 5;

  // A fragments: 2 tiles x 32 rows; lane holds row cl, k-half hi
  const int qbase = b * N + qg * 256 + w * 64;
  bf16x8 af[2];
  #pragma unroll
  for (int a = 0; a < 2; ++a)
    af[a] = *(const bf16x8*)(kvA + (size_t)(qbase + a * 32 + cl) * 16 + hi * 8);

  float rmin[2][16];
  #pragma unroll
  for (int a = 0; a < 2; ++a)
    #pragma unroll
    for (int r = 0; r < 16; ++r) rmin[a][r] = 3.4e38f;

  const f32x16 cz = {0.f, 0.f, 0.f, 0.f, 0.f, 0.f, 0.f, 0.f,
                     0.f, 0.f, 0.f, 0.f, 0.f, 0.f, 0.f, 0.f};
  const int tbase = b * N + c * 2048;

  #pragma unroll 1
  for (int half = 0; half < 2; ++half) {
    if (half) __syncthreads();                       // all waves done with kb
    {   // stage 1024 targets (32 KB)
      const uint4* src = (const uint4*)(kvB + (size_t)(tbase + half * 1024) * 16);
      uint4* dst = (uint4*)kb;
      #pragma unroll
      for (int i = 0; i < 8; ++i) dst[tid + i * 256] = src[tid + i * 256];
    }
    __syncthreads();

    #pragma unroll 1
    for (int jp = 0; jp < 16; ++jp) {               // 2 target tiles per iter
      const ushort* kp = kb + (jp * 64 + cl) * 16 + hi * 8;
      bf16x8 bf0 = *(const bf16x8*)(kp);
      bf16x8 bf1 = *(const bf16x8*)(kp + 32 * 16);
      #pragma unroll
      for (int a = 0; a < 2; ++a) {
        f32x16 acc0 = __builtin_amdgcn_mfma_f32_32x32x16_bf16(af[a], bf0, cz, 0, 0, 0);
        f32x16 acc1 = __builtin_amdgcn_mfma_f32_32x32x16_bf16(af[a], bf1, cz, 0, 0, 0);
        #pragma unroll
        for (int r = 0; r < 16; ++r)
          rmin[a][r] = fminf(rmin[a][r], fminf(acc0[r], acc1[r]));
      }
    }
  }

  // epilogue: per a-tile, transpose via padded LDS (aliases kb; guarded by
  // __syncthreads), per-row fold, plain deterministic store
  #pragma unroll 1
  for (int a = 0; a < 2; ++a) {
    __syncthreads();                                 // kb reads / red reuse done
    #pragma unroll
    for (int r = 0; r < 16; ++r) {
      int row = (r & 3) + 8 * (r >> 2) + 4 * hi;     // m74/m101 C/D layout
      red[w][row][cl] = rmin[a][r];
    }
    __syncthreads();
    if (lane < 32) {
      float m = 3.4e38f;
      #pragma unroll
      for (int i = 0; i < 8; ++i) {
        float4 v = *(const float4*)&red[w][lane][i * 4];
        m = fminf(m, fminf(fminf(v.x, v.y), fminf(v.z, v.w)));
      }
      part[(size_t)c * NQ + dir * BN + qbase + a * 32 + lane] = m;
    }
  }
}

__global__ __launch_bounds__(256) void reduce_final_kernel(
    const float* __restrict__ part, float* __restrict__ blocksums) {
  int gq = blockIdx.x * 256 + threadIdx.x;   // [0, NQ)
  float v = part[gq];
  #pragma unroll
  for (int cc = 1; cc < CO; ++cc) v = fminf(v, part[(size_t)cc * NQ + gq]);
  #pragma unroll
  for (int off = 32; off > 0; off >>= 1) v += __shfl_down(v, off);
  __shared__ float ssum[4];
  const int lane = threadIdx.x & 63, wid = threadIdx.x >> 6;
  if (lane == 0) ssum[wid] = v;
  __syncthreads();
  if (threadIdx.x == 0)
    blocksums[blockIdx.x] = ssum[0] + ssum[1] + ssum[2] + ssum[3];
}

__global__ __launch_bounds__(512) void finalize_sums_kernel(
    const float* __restrict__ blocksums, float* __restrict__ out) {
  float v = blocksums[threadIdx.x];
  #pragma unroll
  for (int off = 32; off > 0; off >>= 1) v += __shfl_down(v, off);
  __shared__ float ssum[8];
  const int lane = threadIdx.x & 63, wid = threadIdx.x >> 6;
  if (lane == 0) ssum[wid] = v;
  __syncthreads();
  if (threadIdx.x == 0) {
    float s = 0.f;
    #pragma unroll
    for (int w = 0; w < 8; ++w) s += ssum[w];
    out[0] = s * (1.0f / 65536.0f);   // mean1 + mean2 (B*N == B*M)
  }
}

// ---------- round-1 proven fallback (if ws too small) ----------
__global__ __launch_bounds__(256) void pack4_kernel(
    const float* __restrict__ xyz1, const float* __restrict__ xyz2,
    float4* __restrict__ p1, float4* __restrict__ p2) {
  int i = blockIdx.x * 256 + threadIdx.x;
  const float* s = (i < BN) ? xyz1 : xyz2;
  float4* d      = (i < BN) ? p1 : p2;
  int j          = (i < BN) ? i : (i - BN);
  float x = s[3 * j], y = s[3 * j + 1], z = s[3 * j + 2];
  d[j] = make_float4(x, y, z, fmaf(x, x, fmaf(y, y, z * z)));
}

__global__ __launch_bounds__(256) void nn_packed_kernel(
    const float4* __restrict__ p1, const float4* __restrict__ p2,
    float* __restrict__ blocksums) {
  const int bid   = blockIdx.x;
  const int dir   = bid >> 8;
  const int idx   = bid & 255;
  const int b     = idx >> 5;
  const int chunk = idx & 31;
  const float4* __restrict__ q = (dir ? p2 : p1) + b * N + chunk * 256;
  const float4* __restrict__ t = (dir ? p1 : p2) + b * N;

  float4 qv = q[threadIdx.x];
  const float qx = -2.0f * qv.x, qy = -2.0f * qv.y, qz = -2.0f * qv.z;

  float mn0 = 3.4e38f, mn1 = 3.4e38f, mn2 = 3.4e38f, mn3 = 3.4e38f;
  #pragma unroll 2
  for (int m = 0; m < N; m += 4) {
    float4 t0 = t[m + 0], t1 = t[m + 1], t2 = t[m + 2], t3 = t[m + 3];
    float d0 = fmaf(qx, t0.x, fmaf(qy, t0.y, fmaf(qz, t0.z, t0.w)));
    float d1 = fmaf(qx, t1.x, fmaf(qy, t1.y, fmaf(qz, t1.z, t1.w)));
    float d2 = fmaf(qx, t2.x, fmaf(qy, t2.y, fmaf(qz, t2.z, t2.w)));
    float d3 = fmaf(qx, t3.x, fmaf(qy, t3.y, fmaf(qz, t3.z, t3.w)));
    mn0 = fminf(mn0, d0); mn1 = fminf(mn1, d1);
    mn2 = fminf(mn2, d2); mn3 = fminf(mn3, d3);
  }
  float v = qv.w + fminf(fminf(mn0, mn1), fminf(mn2, mn3));

  #pragma unroll
  for (int off = 32; off > 0; off >>= 1) v += __shfl_down(v, off);
  __shared__ float ssum[4];
  const int lane = threadIdx.x & 63, wid = threadIdx.x >> 6;
  if (lane == 0) ssum[wid] = v;
  __syncthreads();
  if (threadIdx.x == 0)
    blocksums[bid] = ssum[0] + ssum[1] + ssum[2] + ssum[3];
}

extern "C" void kernel_launch(void* const* d_in, const int* in_sizes, int n_in,
                              void* d_out, int out_size, void* d_ws, size_t ws_size,
                              hipStream_t stream) {
  const float* xyz1 = (const float*)d_in[0];
  const float* xyz2 = (const float*)d_in[1];
  float* out = (float*)d_out;

  // ws: kvA1,kvB1,kvA2,kvB2 (2MB each) | part (CO*NQ f32 = 2MB) | blocksums
  ushort* kvA1 = (ushort*)d_ws;
  ushort* kvB1 = kvA1 + (size_t)BN * 16;
  ushort* kvA2 = kvB1 + (size_t)BN * 16;
  ushort* kvB2 = kvA2 + (size_t)BN * 16;
  float* part = (float*)(kvB2 + (size_t)BN * 16);
  float* blocksums = part + (size_t)CO * NQ;
  const size_t need = (size_t)BN * 16 * 2 * 4 + (size_t)CO * NQ * 4 +
                      512 * sizeof(float);

  if (ws_size >= need) {
    pack_both_kernel<<<(2 * BN) / 256, 256, 0, stream>>>(
        xyz1, xyz2, kvA1, kvB1, kvA2, kvB2);
    nn_mfma32_kernel<<<2048, 256, 0, stream>>>(kvA1, kvB1, kvA2, kvB2, part);
    reduce_final_kernel<<<NQ / 256, 256, 0, stream>>>(part, blocksums);
    finalize_sums_kernel<<<1, 512, 0, stream>>>(blocksums, out);
  } else {
    float4* p1 = (float4*)d_ws;
    float4* p2 = p1 + BN;
    float* bsum = (float*)(p2 + BN);
    pack4_kernel<<<(2 * BN) / 256, 256, 0, stream>>>(xyz1, xyz2, p1, p2);
    nn_packed_kernel<<<512, 256, 0, stream>>>(p1, p2, bsum);
    finalize_sums_kernel<<<1, 512, 0, stream>>>(bsum, out);
  }
}